// Round 5
// baseline (9633.416 us; speedup 1.0000x reference)
//
#include <hip/hip_runtime.h>

#define N_USERS 100000
#define N_ITEMS 200000
#define N_NODES 300000
#define EMB 64
#define NNZ_C 9600000

#define ROWS_PB 1172                 // rows per rowblock (256*1172 = 300032 >= 300000)
#define NRB 256                      // rowblocks == spmm grid == 1 block/CU
#define COLT 30000                   // cols per tile -> slice = 30000*128B = 3.84 MB < 4 MB L2/XCD
#define NT 10                        // coltiles
#define NG 2560                      // groups = NRB*NT
#define NGP 3072                     // padded to 1024*3 for the scans
#define P1_CHUNK 9375                // 256 blocks * 4 chunks * 9375 = 9.6M exactly
#define ACC_STRIDE 33                // 32 dims + 1 pad (33 == 1 mod 32 -> bank spread by row)

// ==================== elementwise (fallback path only) ====================

__global__ void init_kernel(const float4* __restrict__ ue, const float4* __restrict__ ie,
                            float4* __restrict__ ego, float4* __restrict__ acc) {
    const int user4 = N_USERS * EMB / 4;
    const int total4 = N_NODES * EMB / 4;
    int stride = gridDim.x * blockDim.x;
    for (int i = blockIdx.x * blockDim.x + threadIdx.x; i < total4; i += stride) {
        float4 v = (i < user4) ? ue[i] : ie[i - user4];
        ego[i] = v;
        acc[i] = v;
    }
}

__global__ void zero_int_kernel(int* __restrict__ p, int n) {
    int stride = gridDim.x * blockDim.x;
    for (int i = blockIdx.x * blockDim.x + threadIdx.x; i < n; i += stride) p[i] = 0;
}

// ==================== group histogram: bk = (row/1172)*10 + col/30000 ====================

__global__ __launch_bounds__(1024) void ghist_kernel(const int* __restrict__ rows,
                                                     const int* __restrict__ cols,
                                                     int* __restrict__ gcounts) {
    __shared__ int lh[NG];
    for (int i = threadIdx.x; i < NG; i += 1024) lh[i] = 0;
    __syncthreads();
    int stride = gridDim.x * blockDim.x;
    for (int e = blockIdx.x * blockDim.x + threadIdx.x; e < NNZ_C; e += stride) {
        int bk = (rows[e] / ROWS_PB) * NT + (cols[e] / COLT);
        atomicAdd(&lh[bk], 1);
    }
    __syncthreads();
    for (int i = threadIdx.x; i < NG; i += 1024)
        if (lh[i]) atomicAdd(&gcounts[i], lh[i]);
}

// exclusive scan of NGP group counts, single block, 3 elems/thread
// (counts beyond NG are zero, so gbase[NG] == NNZ_C falls out naturally)
__global__ __launch_bounds__(1024) void gscan_kernel(const int* __restrict__ gcounts,
                                                     int* __restrict__ gbase,
                                                     int* __restrict__ gcursor) {
    __shared__ int ts[1024];
    int t = threadIdx.x;
    int c0 = gcounts[3 * t], c1 = gcounts[3 * t + 1], c2 = gcounts[3 * t + 2];
    int s = c0 + c1 + c2;
    ts[t] = s;
    __syncthreads();
    for (int off = 1; off < 1024; off <<= 1) {
        int v = (t >= off) ? ts[t - off] : 0;
        __syncthreads();
        ts[t] += v;
        __syncthreads();
    }
    int excl = ts[t] - s;
    gbase[3 * t] = excl;         gcursor[3 * t] = excl;
    gbase[3 * t + 1] = excl + c0;      gcursor[3 * t + 1] = excl + c0;
    gbase[3 * t + 2] = excl + c0 + c1; gcursor[3 * t + 2] = excl + c0 + c1;
}

// ==================== single-pass LDS multi-split into group-major order ====================
// entry: x = (rowlow<<19)|col  (col<2^19, rowlow<1172<2^11 -> 30 bits), y = val bits

__global__ __launch_bounds__(1024) void gbin_kernel(const int* __restrict__ rows,
                                                    const int* __restrict__ cols,
                                                    const float* __restrict__ vals,
                                                    int* __restrict__ gcursor,
                                                    uint2* __restrict__ cv) {
    __shared__ int lh[NGP];
    __shared__ int lb[NGP];
    __shared__ int gb[NGP];
    __shared__ int ts[1024];
    __shared__ uint2 stg[P1_CHUNK];            // 75 KB
    __shared__ unsigned short sbk[P1_CHUNK];   // 18.3 KB
    int tid = threadIdx.x;
    for (int c = 0; c < 4; ++c) {
        int cb = (blockIdx.x * 4 + c) * P1_CHUNK;
        lh[tid] = 0;
        lh[tid + 1024] = 0;
        lh[tid + 2048] = 0;
        __syncthreads();
        int ebr[10]; unsigned epk[10]; float evl[10];
        #pragma unroll
        for (int j = 0; j < 10; ++j) {
            int i = j * 1024 + tid;
            ebr[j] = -1;
            if (i < P1_CHUNK) {
                int e = cb + i;
                int r = rows[e];
                int cc = cols[e];
                float v = vals[e];
                int bk = (r / ROWS_PB) * NT + (cc / COLT);
                int rk = atomicAdd(&lh[bk], 1);       // rk < 9375 < 2^14
                ebr[j] = (bk << 14) | rk;             // bk < 2560 < 2^12
                epk[j] = ((unsigned)(r % ROWS_PB) << 19) | (unsigned)cc;
                evl[j] = v;
            }
        }
        __syncthreads();
        // scan lh[0..3071] -> lb (exclusive), reserve global space per group
        int c0 = lh[3 * tid], c1 = lh[3 * tid + 1], c2 = lh[3 * tid + 2];
        int s = c0 + c1 + c2;
        ts[tid] = s;
        __syncthreads();
        for (int off = 1; off < 1024; off <<= 1) {
            int v = (tid >= off) ? ts[tid - off] : 0;
            __syncthreads();
            ts[tid] += v;
            __syncthreads();
        }
        int excl = ts[tid] - s;
        lb[3 * tid] = excl;
        lb[3 * tid + 1] = excl + c0;
        lb[3 * tid + 2] = excl + c0 + c1;
        if (c0) gb[3 * tid] = atomicAdd(&gcursor[3 * tid], c0);
        if (c1) gb[3 * tid + 1] = atomicAdd(&gcursor[3 * tid + 1], c1);
        if (c2) gb[3 * tid + 2] = atomicAdd(&gcursor[3 * tid + 2], c2);
        __syncthreads();
        // stage grouped by bucket
        #pragma unroll
        for (int j = 0; j < 10; ++j) {
            if (ebr[j] >= 0) {
                int bk = ebr[j] >> 14, rk = ebr[j] & 16383;
                int idx = lb[bk] + rk;
                stg[idx] = make_uint2(epk[j], __float_as_uint(evl[j]));
                sbk[idx] = (unsigned short)bk;
            }
        }
        __syncthreads();
        // write out grouped (runs ~3.7 edges)
        for (int i = tid; i < P1_CHUNK; i += 1024) {
            int bk = sbk[i];
            cv[gb[bk] + (i - lb[bk])] = stg[i];
        }
        __syncthreads();
    }
}

// ==================== tiled SpMM: L2-resident gather + LDS accumulate ====================
// One block per rowblock (256 blocks = 1 per CU). All blocks sweep coltiles 0..9 in
// lockstep so the live gather slice (3.84 MB) stays resident in each XCD's L2.
// MODE 0: gather node-major ue/ie (dual base, +half*8), MODE 1: gather half-plane,
// MODE 2: gather half-plane, epilogue RMW acc = (acc + s)*0.25.

template<int MODE>
__global__ __launch_bounds__(1024) void spmm_tiled_kernel(
        const int* __restrict__ gbase, const uint2* __restrict__ cv,
        const float4* __restrict__ srcA, const float4* __restrict__ srcB,
        float4* __restrict__ outp, int half) {
    __shared__ float accL[ROWS_PB * ACC_STRIDE];   // 154.7 KB
    int tid = threadIdx.x;
    int rb = blockIdx.x;
    for (int i = tid; i < ROWS_PB * ACC_STRIDE; i += 1024) accL[i] = 0.f;
    __syncthreads();
    int sub = tid >> 3, lane = tid & 7;
    const int h8 = half * 8;
    for (int t = 0; t < NT; ++t) {
        int g = rb * NT + t;
        int beg = gbase[g], end = gbase[g + 1];
        int e = beg + sub;
        for (; e + 128 < end; e += 256) {          // 2 edges in flight per sub
            uint2 p0 = cv[e];
            uint2 p1 = cv[e + 128];
            unsigned col0 = p0.x & 0x7FFFF, rl0 = p0.x >> 19;
            unsigned col1 = p1.x & 0x7FFFF, rl1 = p1.x >> 19;
            const float4 *b0, *b1;
            if (MODE == 0) {
                b0 = (col0 < N_USERS) ? srcA + (size_t)col0 * 16 + h8 : srcB + ((size_t)col0 - N_USERS) * 16 + h8;
                b1 = (col1 < N_USERS) ? srcA + (size_t)col1 * 16 + h8 : srcB + ((size_t)col1 - N_USERS) * 16 + h8;
            } else {
                b0 = srcA + (size_t)col0 * 8;
                b1 = srcA + (size_t)col1 * 8;
            }
            float4 x0 = b0[lane];
            float4 x1 = b1[lane];
            float v0 = __uint_as_float(p0.y);
            float v1 = __uint_as_float(p1.y);
            float* a0 = &accL[rl0 * ACC_STRIDE + lane * 4];
            float* a1 = &accL[rl1 * ACC_STRIDE + lane * 4];
            atomicAdd(a0 + 0, v0 * x0.x); atomicAdd(a0 + 1, v0 * x0.y);
            atomicAdd(a0 + 2, v0 * x0.z); atomicAdd(a0 + 3, v0 * x0.w);
            atomicAdd(a1 + 0, v1 * x1.x); atomicAdd(a1 + 1, v1 * x1.y);
            atomicAdd(a1 + 2, v1 * x1.z); atomicAdd(a1 + 3, v1 * x1.w);
        }
        if (e < end) {
            uint2 p0 = cv[e];
            unsigned col0 = p0.x & 0x7FFFF, rl0 = p0.x >> 19;
            const float4* b0;
            if (MODE == 0) {
                b0 = (col0 < N_USERS) ? srcA + (size_t)col0 * 16 + h8 : srcB + ((size_t)col0 - N_USERS) * 16 + h8;
            } else {
                b0 = srcA + (size_t)col0 * 8;
            }
            float4 x0 = b0[lane];
            float v0 = __uint_as_float(p0.y);
            float* a0 = &accL[rl0 * ACC_STRIDE + lane * 4];
            atomicAdd(a0 + 0, v0 * x0.x); atomicAdd(a0 + 1, v0 * x0.y);
            atomicAdd(a0 + 2, v0 * x0.z); atomicAdd(a0 + 3, v0 * x0.w);
        }
        __syncthreads();                           // keep block tile-aligned
    }
    // epilogue: write 1172 rows x 8 float4
    int rowbase = rb * ROWS_PB;
    for (int k = tid; k < ROWS_PB * 8; k += 1024) {
        int rl = k >> 3, j = k & 7;
        int r = rowbase + rl;
        if (r < N_NODES) {
            const float* a = &accL[rl * ACC_STRIDE + j * 4];
            float4 s = make_float4(a[0], a[1], a[2], a[3]);
            if (MODE == 2) {
                int o = r * 16 + h8 + j;
                float4 q = outp[o];
                s.x = (q.x + s.x) * 0.25f;
                s.y = (q.y + s.y) * 0.25f;
                s.z = (q.z + s.z) * 0.25f;
                s.w = (q.w + s.w) * 0.25f;
                outp[o] = s;
            } else {
                outp[r * 8 + j] = s;
            }
        }
    }
}

// ==================== per-half partial merge: acc_half = e0 + e1 + e2 ====================

__global__ __launch_bounds__(256) void mergeh_kernel(const float4* __restrict__ ue,
                                                     const float4* __restrict__ ie,
                                                     const float4* __restrict__ e1h,
                                                     const float4* __restrict__ e2h,
                                                     float4* __restrict__ acc, int half) {
    const int user4 = N_USERS * 16;
    const int totalh = N_NODES * 8;
    int stride = gridDim.x * blockDim.x;
    for (int k = blockIdx.x * blockDim.x + threadIdx.x; k < totalh; k += stride) {
        int n = k >> 3, j = k & 7;
        int o = n * 16 + half * 8 + j;                 // node-major f4 index
        float4 v = (o < user4) ? ue[o] : ie[o - user4];
        float4 a = e1h[k];
        float4 b = e2h[k];
        v.x += a.x + b.x;
        v.y += a.y + b.y;
        v.z += a.z + b.z;
        v.w += a.w + b.w;
        acc[o] = v;
    }
}

// ==================== fallback (atomic path) ====================

__global__ void zero4_kernel(float4* __restrict__ p, int n4) {
    int stride = gridDim.x * blockDim.x;
    float4 z = make_float4(0.f, 0.f, 0.f, 0.f);
    for (int i = blockIdx.x * blockDim.x + threadIdx.x; i < n4; i += stride) p[i] = z;
}

__global__ void spmm_atomic_kernel(const int* __restrict__ rows, const int* __restrict__ cols,
                                   const float* __restrict__ vals,
                                   const float* __restrict__ ego_in, float* __restrict__ ego_out) {
    int wave = (blockIdx.x * blockDim.x + threadIdx.x) >> 6;
    int lane = threadIdx.x & 63;
    int nwaves = (gridDim.x * blockDim.x) >> 6;
    for (int e = wave; e < NNZ_C; e += nwaves) {
        int r = rows[e];
        int c = cols[e];
        float v = vals[e];
        float x = ego_in[c * EMB + lane];
        atomicAdd(&ego_out[r * EMB + lane], v * x);
    }
}

__global__ void add_kernel(float4* __restrict__ acc, const float4* __restrict__ ego,
                           float scale, int n4) {
    int stride = gridDim.x * blockDim.x;
    for (int i = blockIdx.x * blockDim.x + threadIdx.x; i < n4; i += stride) {
        float4 a = acc[i];
        float4 g = ego[i];
        a.x = (a.x + g.x) * scale;
        a.y = (a.y + g.y) * scale;
        a.z = (a.z + g.z) * scale;
        a.w = (a.w + g.w) * scale;
        acc[i] = a;
    }
}

// ==================== launch ====================

extern "C" void kernel_launch(void* const* d_in, const int* in_sizes, int n_in,
                              void* d_out, int out_size, void* d_ws, size_t ws_size,
                              hipStream_t stream) {
    const float* user_emb = (const float*)d_in[0];
    const float* item_emb = (const float*)d_in[1];
    const int*   adj_rows = (const int*)d_in[2];
    const int*   adj_cols = (const int*)d_in[3];
    const float* adj_vals = (const float*)d_in[4];
    float* acc = (float*)d_out;

    const size_t egoN = (size_t)N_NODES * EMB;               // 19.2M floats
    float* ego_a = (float*)d_ws;                             // e1 planes [half][node][32]
    float* ego_b = ego_a + egoN;                             // e2 planes [half][node][32]

    const int total4 = N_NODES * EMB / 4;
    const int EW_BLOCKS = 4096, EW_THREADS = 256;

    // workspace layout
    uint2* cv      = (uint2*)(ego_b + egoN);                 // 76.8 MB group-major (rowlow|col,val)
    int* gcounts   = (int*)(cv + (size_t)NNZ_C);             // NGP
    int* gbase     = gcounts + NGP;                          // NGP (sentinel at NG falls out)
    int* gcursor   = gbase + NGP;                            // NGP
    size_t needed  = (size_t)((char*)(gcursor + NGP) - (char*)d_ws);

    if (ws_size >= needed) {
        // ---- group edges by (rowblock, coltile): hist -> scan -> single multi-split ----
        zero_int_kernel<<<3, 1024, 0, stream>>>(gcounts, NGP);
        ghist_kernel<<<512, 1024, 0, stream>>>(adj_rows, adj_cols, gcounts);
        gscan_kernel<<<1, 1024, 0, stream>>>(gcounts, gbase, gcursor);
        gbin_kernel<<<256, 1024, 0, stream>>>(adj_rows, adj_cols, adj_vals, gcursor, cv);

        // ---- per-half chains: L1 -> L2 -> merge(e0+e1+e2) -> L3 (RMW *0.25) ----
        const float4* ue4 = (const float4*)user_emb;
        const float4* ie4 = (const float4*)item_emb;
        const size_t planeF4 = (size_t)N_NODES * 8;          // 38.4 MB per half-plane

        for (int h = 0; h < 2; ++h) {
            float4* e1h = (float4*)ego_a + h * planeF4;
            float4* e2h = (float4*)ego_b + h * planeF4;
            spmm_tiled_kernel<0><<<NRB, 1024, 0, stream>>>(gbase, cv, ue4, ie4, e1h, h);
            spmm_tiled_kernel<1><<<NRB, 1024, 0, stream>>>(gbase, cv,
                                                           (const float4*)e1h, nullptr, e2h, h);
            mergeh_kernel<<<2048, 256, 0, stream>>>(ue4, ie4,
                                                    (const float4*)e1h, (const float4*)e2h,
                                                    (float4*)acc, h);
            spmm_tiled_kernel<2><<<NRB, 1024, 0, stream>>>(gbase, cv,
                                                           (const float4*)e2h, nullptr,
                                                           (float4*)acc, h);
        }
    } else {
        // ---- fallback: atomic COO path ----
        init_kernel<<<EW_BLOCKS, EW_THREADS, 0, stream>>>(
            (const float4*)user_emb, (const float4*)item_emb,
            (float4*)ego_a, (float4*)acc);
        float* ego_in = ego_a;
        float* ego_out = ego_b;
        for (int layer = 0; layer < 3; ++layer) {
            zero4_kernel<<<EW_BLOCKS, EW_THREADS, 0, stream>>>((float4*)ego_out, total4);
            spmm_atomic_kernel<<<4096, 256, 0, stream>>>(
                adj_rows, adj_cols, adj_vals, ego_in, ego_out);
            float scale = (layer == 2) ? 0.25f : 1.0f;
            add_kernel<<<EW_BLOCKS, EW_THREADS, 0, stream>>>(
                (float4*)acc, (const float4*)ego_out, scale, total4);
            float* t = ego_in; ego_in = ego_out; ego_out = t;
        }
    }
}

// Round 7
// 2529.641 us; speedup vs baseline: 3.8082x; 3.8082x over previous
//
#include <hip/hip_runtime.h>

#define N_USERS 100000
#define N_ITEMS 200000
#define N_NODES 300000
#define EMB 64
#define NNZ_C 9600000

#define ROWS_PB 1172                 // rows per rowblock (256*1172 = 300032 >= 300000)
#define NRB 256                      // rowblocks == spmm grid == 1 block/CU
#define COLT 30000                   // cols per tile -> slice = 30000*128B = 3.84 MB < 4 MB L2/XCD
#define NT 10                        // coltiles
#define NG 2560                      // groups = NT*NRB
#define NGP 3072                     // padded to 1024*3 for the scans
#define P1_CHUNK 9375                // 256 blocks * 4 chunks * 9375 = 9.6M exactly
#define SEGSTRIDE 1173               // per-group seg entries (1172 + total)

// ==================== elementwise (fallback path only) ====================

__global__ void init_kernel(const float4* __restrict__ ue, const float4* __restrict__ ie,
                            float4* __restrict__ ego, float4* __restrict__ acc) {
    const int user4 = N_USERS * EMB / 4;
    const int total4 = N_NODES * EMB / 4;
    int stride = gridDim.x * blockDim.x;
    for (int i = blockIdx.x * blockDim.x + threadIdx.x; i < total4; i += stride) {
        float4 v = (i < user4) ? ue[i] : ie[i - user4];
        ego[i] = v;
        acc[i] = v;
    }
}

__global__ void zero_int_kernel(int* __restrict__ p, int n) {
    int stride = gridDim.x * blockDim.x;
    for (int i = blockIdx.x * blockDim.x + threadIdx.x; i < n; i += stride) p[i] = 0;
}

// ==================== group histogram: bk = (col/30000)*256 + row/1172 ====================

__global__ __launch_bounds__(1024) void ghist_kernel(const int* __restrict__ rows,
                                                     const int* __restrict__ cols,
                                                     int* __restrict__ gcounts) {
    __shared__ int lh[NG];
    for (int i = threadIdx.x; i < NG; i += 1024) lh[i] = 0;
    __syncthreads();
    int stride = gridDim.x * blockDim.x;
    for (int e = blockIdx.x * blockDim.x + threadIdx.x; e < NNZ_C; e += stride) {
        int bk = (cols[e] / COLT) * NRB + (rows[e] / ROWS_PB);
        atomicAdd(&lh[bk], 1);
    }
    __syncthreads();
    for (int i = threadIdx.x; i < NG; i += 1024)
        if (lh[i]) atomicAdd(&gcounts[i], lh[i]);
}

// exclusive scan of NGP group counts, single block, 3 elems/thread
// (counts beyond NG are zero, so gbase[NG] == NNZ_C falls out naturally)
__global__ __launch_bounds__(1024) void gscan_kernel(const int* __restrict__ gcounts,
                                                     int* __restrict__ gbase,
                                                     int* __restrict__ gcursor) {
    __shared__ int ts[1024];
    int t = threadIdx.x;
    int c0 = gcounts[3 * t], c1 = gcounts[3 * t + 1], c2 = gcounts[3 * t + 2];
    int s = c0 + c1 + c2;
    ts[t] = s;
    __syncthreads();
    for (int off = 1; off < 1024; off <<= 1) {
        int v = (t >= off) ? ts[t - off] : 0;
        __syncthreads();
        ts[t] += v;
        __syncthreads();
    }
    int excl = ts[t] - s;
    gbase[3 * t] = excl;               gcursor[3 * t] = excl;
    gbase[3 * t + 1] = excl + c0;      gcursor[3 * t + 1] = excl + c0;
    gbase[3 * t + 2] = excl + c0 + c1; gcursor[3 * t + 2] = excl + c0 + c1;
}

// ==================== single-pass LDS multi-split into group-major order ====================
// entry: x = (rowlow<<19)|col  (col<2^19, rowlow<1172<2^11 -> 30 bits), y = val bits

__global__ __launch_bounds__(1024) void gbin_kernel(const int* __restrict__ rows,
                                                    const int* __restrict__ cols,
                                                    const float* __restrict__ vals,
                                                    int* __restrict__ gcursor,
                                                    uint2* __restrict__ cvt) {
    __shared__ int lh[NGP];
    __shared__ int lb[NGP];
    __shared__ int gb[NGP];
    __shared__ int ts[1024];
    __shared__ uint2 stg[P1_CHUNK];            // 75 KB
    __shared__ unsigned short sbk[P1_CHUNK];   // 18.3 KB
    int tid = threadIdx.x;
    for (int c = 0; c < 4; ++c) {
        int cb = (blockIdx.x * 4 + c) * P1_CHUNK;
        lh[tid] = 0;
        lh[tid + 1024] = 0;
        lh[tid + 2048] = 0;
        __syncthreads();
        int ebr[10]; unsigned epk[10]; float evl[10];
        #pragma unroll
        for (int j = 0; j < 10; ++j) {
            int i = j * 1024 + tid;
            ebr[j] = -1;
            if (i < P1_CHUNK) {
                int e = cb + i;
                int r = rows[e];
                int cc = cols[e];
                float v = vals[e];
                int bk = (cc / COLT) * NRB + (r / ROWS_PB);
                int rk = atomicAdd(&lh[bk], 1);       // rk < 9375 < 2^14
                ebr[j] = (bk << 14) | rk;             // bk < 2560 < 2^12
                epk[j] = ((unsigned)(r % ROWS_PB) << 19) | (unsigned)cc;
                evl[j] = v;
            }
        }
        __syncthreads();
        // scan lh[0..3071] -> lb (exclusive), reserve global space per group
        int c0 = lh[3 * tid], c1 = lh[3 * tid + 1], c2 = lh[3 * tid + 2];
        int s = c0 + c1 + c2;
        ts[tid] = s;
        __syncthreads();
        for (int off = 1; off < 1024; off <<= 1) {
            int v = (tid >= off) ? ts[tid - off] : 0;
            __syncthreads();
            ts[tid] += v;
            __syncthreads();
        }
        int excl = ts[tid] - s;
        lb[3 * tid] = excl;
        lb[3 * tid + 1] = excl + c0;
        lb[3 * tid + 2] = excl + c0 + c1;
        if (c0) gb[3 * tid] = atomicAdd(&gcursor[3 * tid], c0);
        if (c1) gb[3 * tid + 1] = atomicAdd(&gcursor[3 * tid + 1], c1);
        if (c2) gb[3 * tid + 2] = atomicAdd(&gcursor[3 * tid + 2], c2);
        __syncthreads();
        // stage grouped by bucket
        #pragma unroll
        for (int j = 0; j < 10; ++j) {
            if (ebr[j] >= 0) {
                int bk = ebr[j] >> 14, rk = ebr[j] & 16383;
                int idx = lb[bk] + rk;
                stg[idx] = make_uint2(epk[j], __float_as_uint(evl[j]));
                sbk[idx] = (unsigned short)bk;
            }
        }
        __syncthreads();
        // write out grouped (runs ~3.7 edges)
        for (int i = tid; i < P1_CHUNK; i += 1024) {
            int bk = sbk[i];
            cvt[gb[bk] + (i - lb[bk])] = stg[i];
        }
        __syncthreads();
    }
}

// ==================== per-group row sort + seg16 build ====================
// One block per group. Row-histogram in LDS (1 atomic/edge), scan, direct global
// scatter: target is the group's own ~30 KB slice -> L2 absorbs the 8B writes.

__global__ __launch_bounds__(1024) void place2_kernel(const int* __restrict__ gbase,
                                                      const uint2* __restrict__ cvt,
                                                      uint2* __restrict__ cv,
                                                      unsigned short* __restrict__ seg) {
    __shared__ int hist[ROWS_PB];
    __shared__ int cur[ROWS_PB];
    __shared__ int ts[1024];
    int g = blockIdx.x, tid = threadIdx.x;
    int beg = gbase[g], end = gbase[g + 1];
    unsigned short* sg = seg + (size_t)g * SEGSTRIDE;

    for (int i = tid; i < ROWS_PB; i += 1024) hist[i] = 0;
    __syncthreads();
    for (int e = beg + tid; e < end; e += 1024)
        atomicAdd(&hist[cvt[e].x >> 19], 1);
    __syncthreads();
    // exclusive scan of 1172 counts (2 per thread, Hillis-Steele over pair sums)
    int c0 = (2 * tid < ROWS_PB) ? hist[2 * tid] : 0;
    int c1 = (2 * tid + 1 < ROWS_PB) ? hist[2 * tid + 1] : 0;
    int s = c0 + c1;
    ts[tid] = s;
    __syncthreads();
    for (int off = 1; off < 1024; off <<= 1) {
        int v = (tid >= off) ? ts[tid - off] : 0;
        __syncthreads();
        ts[tid] += v;
        __syncthreads();
    }
    int excl = ts[tid] - s;
    if (2 * tid < ROWS_PB)     { sg[2 * tid] = (unsigned short)excl;            cur[2 * tid] = beg + excl; }
    if (2 * tid + 1 < ROWS_PB) { sg[2 * tid + 1] = (unsigned short)(excl + c0); cur[2 * tid + 1] = beg + excl + c0; }
    if (tid == 0) sg[ROWS_PB] = (unsigned short)(end - beg);
    __syncthreads();
    // scatter into row-sorted position within the group slice
    for (int e = beg + tid; e < end; e += 1024) {
        uint2 p = cvt[e];
        int pos = atomicAdd(&cur[p.x >> 19], 1);
        cv[pos] = p;
    }
}

// ==================== tiled SpMM: L2-resident gather + REGISTER accumulate ====================
// 256 blocks (1/CU, enforced by LDS guard) x 1024 threads; 8-lane sub owns rows
// k*128+sub of its 1172-row block (10 float4 acc slots). Blocks sweep coltiles in
// lockstep so the live 3.84 MB gather slice stays L2-resident. No LDS ops on the
// edge path; accumulation is pure FMA into registers.
// MODE 0: gather node-major ue/ie (dual base, +half*8). MODE 1: gather half-plane.
// MODE 2: gather half-plane, epilogue RMW acc = (acc + s)*0.25.

template<int MODE>
__global__ __launch_bounds__(1024) void spmm_reg_kernel(
        const int* __restrict__ gbase, const unsigned short* __restrict__ seg,
        const uint2* __restrict__ cv,
        const float4* __restrict__ srcA, const float4* __restrict__ srcB,
        float4* __restrict__ outp, int half) {
    __shared__ float lds_guard[21504];            // 84 KB: force 1 block/CU
    int tid = threadIdx.x, rb = blockIdx.x;
    if (gbase[NG] == -12345) lds_guard[tid] = 0.f;   // never true; defeats DCE
    int sub = tid >> 3, lane = tid & 7;
    const int h8 = half * 8;
    float4 acc[10];
    #pragma unroll
    for (int k = 0; k < 10; ++k) acc[k] = make_float4(0.f, 0.f, 0.f, 0.f);
    for (int t = 0; t < NT; ++t) {
        int g = t * NRB + rb;
        int base = gbase[g];
        const unsigned short* sg = seg + (size_t)g * SEGSTRIDE;
        #pragma unroll
        for (int k = 0; k < 10; ++k) {
            int rl = k * 128 + sub;
            if (rl < ROWS_PB) {
                int lo = base + sg[rl], hi = base + sg[rl + 1];
                for (int e = lo; e < hi; ++e) {
                    uint2 p = cv[e];
                    unsigned col = p.x & 0x7FFFF;
                    const float4* b;
                    if (MODE == 0) {
                        b = (col < N_USERS) ? srcA + (size_t)col * 16 + h8
                                            : srcB + ((size_t)col - N_USERS) * 16 + h8;
                    } else {
                        b = srcA + (size_t)col * 8;
                    }
                    float4 x = b[lane];
                    float v = __uint_as_float(p.y);
                    acc[k].x += v * x.x; acc[k].y += v * x.y;
                    acc[k].z += v * x.z; acc[k].w += v * x.w;
                }
            }
        }
        __syncthreads();                           // lockstep: keep slice L2-resident
    }
    // epilogue: each sub writes its rows (8 lanes x 16B = 128B contiguous per row)
    int rowbase = rb * ROWS_PB;
    #pragma unroll
    for (int k = 0; k < 10; ++k) {
        int rl = k * 128 + sub;
        int r = rowbase + rl;
        if (rl < ROWS_PB && r < N_NODES) {
            float4 s = acc[k];
            if (MODE == 2) {
                int o = r * 16 + h8 + lane;
                float4 q = outp[o];
                s.x = (q.x + s.x) * 0.25f;
                s.y = (q.y + s.y) * 0.25f;
                s.z = (q.z + s.z) * 0.25f;
                s.w = (q.w + s.w) * 0.25f;
                outp[o] = s;
            } else {
                outp[r * 8 + lane] = s;
            }
        }
    }
}

// ==================== per-half partial merge: acc_half = e0 + e1 + e2 ====================

__global__ __launch_bounds__(256) void mergeh_kernel(const float4* __restrict__ ue,
                                                     const float4* __restrict__ ie,
                                                     const float4* __restrict__ e1h,
                                                     const float4* __restrict__ e2h,
                                                     float4* __restrict__ acc, int half) {
    const int user4 = N_USERS * 16;
    const int totalh = N_NODES * 8;
    int stride = gridDim.x * blockDim.x;
    for (int k = blockIdx.x * blockDim.x + threadIdx.x; k < totalh; k += stride) {
        int n = k >> 3, j = k & 7;
        int o = n * 16 + half * 8 + j;                 // node-major f4 index
        float4 v = (o < user4) ? ue[o] : ie[o - user4];
        float4 a = e1h[k];
        float4 b = e2h[k];
        v.x += a.x + b.x;
        v.y += a.y + b.y;
        v.z += a.z + b.z;
        v.w += a.w + b.w;
        acc[o] = v;
    }
}

// ==================== fallback (atomic path) ====================

__global__ void zero4_kernel(float4* __restrict__ p, int n4) {
    int stride = gridDim.x * blockDim.x;
    float4 z = make_float4(0.f, 0.f, 0.f, 0.f);
    for (int i = blockIdx.x * blockDim.x + threadIdx.x; i < n4; i += stride) p[i] = z;
}

__global__ void spmm_atomic_kernel(const int* __restrict__ rows, const int* __restrict__ cols,
                                   const float* __restrict__ vals,
                                   const float* __restrict__ ego_in, float* __restrict__ ego_out) {
    int wave = (blockIdx.x * blockDim.x + threadIdx.x) >> 6;
    int lane = threadIdx.x & 63;
    int nwaves = (gridDim.x * blockDim.x) >> 6;
    for (int e = wave; e < NNZ_C; e += nwaves) {
        int r = rows[e];
        int c = cols[e];
        float v = vals[e];
        float x = ego_in[c * EMB + lane];
        atomicAdd(&ego_out[r * EMB + lane], v * x);
    }
}

__global__ void add_kernel(float4* __restrict__ acc, const float4* __restrict__ ego,
                           float scale, int n4) {
    int stride = gridDim.x * blockDim.x;
    for (int i = blockIdx.x * blockDim.x + threadIdx.x; i < n4; i += stride) {
        float4 a = acc[i];
        float4 g = ego[i];
        a.x = (a.x + g.x) * scale;
        a.y = (a.y + g.y) * scale;
        a.z = (a.z + g.z) * scale;
        a.w = (a.w + g.w) * scale;
        acc[i] = a;
    }
}

// ==================== launch ====================

extern "C" void kernel_launch(void* const* d_in, const int* in_sizes, int n_in,
                              void* d_out, int out_size, void* d_ws, size_t ws_size,
                              hipStream_t stream) {
    const float* user_emb = (const float*)d_in[0];
    const float* item_emb = (const float*)d_in[1];
    const int*   adj_rows = (const int*)d_in[2];
    const int*   adj_cols = (const int*)d_in[3];
    const float* adj_vals = (const float*)d_in[4];
    float* acc = (float*)d_out;

    const size_t egoN = (size_t)N_NODES * EMB;               // 19.2M floats
    float* ego_a = (float*)d_ws;                             // e1 planes [half][node][32]
    float* ego_b = ego_a + egoN;                             // e2 planes [half][node][32]

    const int total4 = N_NODES * EMB / 4;
    const int EW_BLOCKS = 4096, EW_THREADS = 256;

    // workspace layout
    uint2* cvt     = (uint2*)ego_b;                          // alias: group-major temp
                                                             // (dead before e2 is written)
    uint2* cv      = (uint2*)(ego_b + egoN);                 // 76.8 MB (t,rb)-major row-sorted
    int* gcounts   = (int*)(cv + (size_t)NNZ_C);             // NGP
    int* gbase     = gcounts + NGP;                          // NGP (gbase[NG] == NNZ_C)
    int* gcursor   = gbase + NGP;                            // NGP
    unsigned short* seg16 = (unsigned short*)(gcursor + NGP); // NG*1173 ushorts (~6 MB)
    size_t needed  = (size_t)((char*)(seg16 + (size_t)NG * SEGSTRIDE + 16) - (char*)d_ws);

    if (ws_size >= needed) {
        // ---- group by (coltile, rowblock), then row-sort within group ----
        zero_int_kernel<<<3, 1024, 0, stream>>>(gcounts, NGP);
        ghist_kernel<<<512, 1024, 0, stream>>>(adj_rows, adj_cols, gcounts);
        gscan_kernel<<<1, 1024, 0, stream>>>(gcounts, gbase, gcursor);
        gbin_kernel<<<256, 1024, 0, stream>>>(adj_rows, adj_cols, adj_vals, gcursor, cvt);
        place2_kernel<<<NG, 1024, 0, stream>>>(gbase, cvt, cv, seg16);

        // ---- per-half chains: L1 -> L2 -> merge(e0+e1+e2) -> L3 (RMW *0.25) ----
        const float4* ue4 = (const float4*)user_emb;
        const float4* ie4 = (const float4*)item_emb;
        const size_t planeF4 = (size_t)N_NODES * 8;          // 38.4 MB per half-plane

        for (int h = 0; h < 2; ++h) {
            float4* e1h = (float4*)ego_a + h * planeF4;
            float4* e2h = (float4*)ego_b + h * planeF4;
            spmm_reg_kernel<0><<<NRB, 1024, 0, stream>>>(gbase, seg16, cv, ue4, ie4, e1h, h);
            spmm_reg_kernel<1><<<NRB, 1024, 0, stream>>>(gbase, seg16, cv,
                                                         (const float4*)e1h, nullptr, e2h, h);
            mergeh_kernel<<<2048, 256, 0, stream>>>(ue4, ie4,
                                                    (const float4*)e1h, (const float4*)e2h,
                                                    (float4*)acc, h);
            spmm_reg_kernel<2><<<NRB, 1024, 0, stream>>>(gbase, seg16, cv,
                                                         (const float4*)e2h, nullptr,
                                                         (float4*)acc, h);
        }
    } else {
        // ---- fallback: atomic COO path ----
        init_kernel<<<EW_BLOCKS, EW_THREADS, 0, stream>>>(
            (const float4*)user_emb, (const float4*)item_emb,
            (float4*)ego_a, (float4*)acc);
        float* ego_in = ego_a;
        float* ego_out = ego_b;
        for (int layer = 0; layer < 3; ++layer) {
            zero4_kernel<<<EW_BLOCKS, EW_THREADS, 0, stream>>>((float4*)ego_out, total4);
            spmm_atomic_kernel<<<4096, 256, 0, stream>>>(
                adj_rows, adj_cols, adj_vals, ego_in, ego_out);
            float scale = (layer == 2) ? 0.25f : 1.0f;
            add_kernel<<<EW_BLOCKS, EW_THREADS, 0, stream>>>(
                (float4*)acc, (const float4*)ego_out, scale, total4);
            float* t = ego_in; ego_in = ego_out; ego_out = t;
        }
    }
}